// Round 1
// baseline (3633.978 us; speedup 1.0000x reference)
//
#include <hip/hip_runtime.h>
#include <hip/hip_bf16.h>
#include <cstdint>
#include <cstddef>

#define HID   1024
#define G4    4096   // 4*HID
#define BB    64     // batch
#define TSEQ  128    // T
#define NSTEP 127    // T-1 steps

union F4 { float4 v; float f[4]; };

__device__ __forceinline__ float sigm(float x) { return 1.0f / (1.0f + expf(-x)); }

// ---------------------------------------------------------------------------
// Kernel 1: fused embedding gather + input GEMM.
// Gin[m][n] = sum_k emb[tgt[b][t0+tl]][k] * w_ih[n][k] + b_ih[n] + b_hh[n]
// where m = tl*64 + b, M = tc*64, N = 4096, K = 1024.
// Tile 128x128, 256 threads, 8x8 micro-tile, K-chunk 32 staged in LDS.
// ---------------------------------------------------------------------------
__global__ __launch_bounds__(256) void gin_gemm(
    const int* __restrict__ tgt, const float* __restrict__ emb,
    const float* __restrict__ w_ih, const float* __restrict__ b_ih,
    const float* __restrict__ b_hh, float* __restrict__ gin,
    int t0, int tc)
{
  const int M  = tc * BB;
  const int m0 = blockIdx.x * 128;
  const int n0 = blockIdx.y * 128;
  const int tid = threadIdx.x;

  __shared__ float As[32][132];   // [k][m], padded
  __shared__ float Bs[32][132];   // [k][n], padded

  float acc[8][8];
#pragma unroll
  for (int i = 0; i < 8; ++i)
#pragma unroll
    for (int j = 0; j < 8; ++j) acc[i][j] = 0.0f;

  const int tx = tid & 15;   // n-group (8 cols each)
  const int ty = tid >> 4;   // m-group (8 rows each)

  for (int kc = 0; kc < HID; kc += 32) {
    // --- load A tile (gathered embedding rows), transposed into LDS ---
#pragma unroll
    for (int it = 0; it < 4; ++it) {
      int f  = tid + it * 256;      // float4 index in [0,1024)
      int r  = f >> 3;              // row in tile [0,128)
      int kq = f & 7;               // float4 within 32-k chunk
      int m  = m0 + r;
      float4 v = make_float4(0.f, 0.f, 0.f, 0.f);
      if (m < M) {
        int b  = m & 63;
        int tl = m >> 6;
        int tok = tgt[b * TSEQ + (t0 + tl)];
        if (tok != 0) {
          v = *reinterpret_cast<const float4*>(&emb[(size_t)tok * HID + kc + kq * 4]);
        }
      }
      int k4 = kq * 4;
      As[k4 + 0][r] = v.x; As[k4 + 1][r] = v.y;
      As[k4 + 2][r] = v.z; As[k4 + 3][r] = v.w;
    }
    // --- load B tile (w_ih rows), transposed into LDS ---
#pragma unroll
    for (int it = 0; it < 4; ++it) {
      int f  = tid + it * 256;
      int r  = f >> 3;
      int kq = f & 7;
      float4 v = *reinterpret_cast<const float4*>(
          &w_ih[(size_t)(n0 + r) * HID + kc + kq * 4]);
      int k4 = kq * 4;
      Bs[k4 + 0][r] = v.x; Bs[k4 + 1][r] = v.y;
      Bs[k4 + 2][r] = v.z; Bs[k4 + 3][r] = v.w;
    }
    __syncthreads();

#pragma unroll 8
    for (int k = 0; k < 32; ++k) {
      float a[8], bb[8];
      *(float4*)&a[0]  = *(const float4*)&As[k][ty * 8];
      *(float4*)&a[4]  = *(const float4*)&As[k][ty * 8 + 4];
      *(float4*)&bb[0] = *(const float4*)&Bs[k][tx * 8];
      *(float4*)&bb[4] = *(const float4*)&Bs[k][tx * 8 + 4];
#pragma unroll
      for (int i = 0; i < 8; ++i)
#pragma unroll
        for (int j = 0; j < 8; ++j)
          acc[i][j] = fmaf(a[i], bb[j], acc[i][j]);
    }
    __syncthreads();
  }

  // epilogue: add biases, store
  float bias[8];
#pragma unroll
  for (int j = 0; j < 8; ++j) {
    int n = n0 + tx * 8 + j;
    bias[j] = b_ih[n] + b_hh[n];
  }
#pragma unroll
  for (int i = 0; i < 8; ++i) {
    int m = m0 + ty * 8 + i;
    if (m < M) {
      float* dst = &gin[(size_t)m * G4 + n0 + tx * 8];
      *(float4*)dst       = make_float4(acc[i][0] + bias[0], acc[i][1] + bias[1],
                                        acc[i][2] + bias[2], acc[i][3] + bias[3]);
      *(float4*)(dst + 4) = make_float4(acc[i][4] + bias[4], acc[i][5] + bias[5],
                                        acc[i][6] + bias[6], acc[i][7] + bias[7]);
    }
  }
}

// ---------------------------------------------------------------------------
// Kernel 2: recurrent GEMM partial: part[ks][b][n] = sum_{k in slice ks}
//           h_state[b][k] * w_hh[n][k].   grid = (8 k-slices, 32 n-tiles)
// Tile: 64 batch x 128 units, K-slice 128, 256 threads, 4x8 micro-tile.
// ---------------------------------------------------------------------------
__global__ __launch_bounds__(256) void step_gemm(
    const float* __restrict__ h_state, const float* __restrict__ w_hh,
    float* __restrict__ part)
{
  const int ks = blockIdx.x;          // k slice [0,8)
  const int n0 = blockIdx.y * 128;
  const int k0 = ks * 128;
  const int tid = threadIdx.x;

  __shared__ float Hs[32][68];    // [k][b]
  __shared__ float Ws[32][132];   // [k][n]

  float acc[4][8];
#pragma unroll
  for (int i = 0; i < 4; ++i)
#pragma unroll
    for (int j = 0; j < 8; ++j) acc[i][j] = 0.0f;

  const int tx = tid & 15;   // n-group (8 cols)
  const int ty = tid >> 4;   // b-group (4 rows)

  for (int kc = 0; kc < 128; kc += 32) {
    // h chunk: 64 rows x 32 k = 512 float4
#pragma unroll
    for (int it = 0; it < 2; ++it) {
      int f  = tid + it * 256;
      int r  = f >> 3;
      int kq = f & 7;
      float4 v = *reinterpret_cast<const float4*>(
          &h_state[(size_t)r * HID + k0 + kc + kq * 4]);
      int k4 = kq * 4;
      Hs[k4 + 0][r] = v.x; Hs[k4 + 1][r] = v.y;
      Hs[k4 + 2][r] = v.z; Hs[k4 + 3][r] = v.w;
    }
    // w chunk: 128 rows x 32 k
#pragma unroll
    for (int it = 0; it < 4; ++it) {
      int f  = tid + it * 256;
      int r  = f >> 3;
      int kq = f & 7;
      float4 v = *reinterpret_cast<const float4*>(
          &w_hh[(size_t)(n0 + r) * HID + k0 + kc + kq * 4]);
      int k4 = kq * 4;
      Ws[k4 + 0][r] = v.x; Ws[k4 + 1][r] = v.y;
      Ws[k4 + 2][r] = v.z; Ws[k4 + 3][r] = v.w;
    }
    __syncthreads();

#pragma unroll 8
    for (int k = 0; k < 32; ++k) {
      float a[4], bb[8];
      *(float4*)&a[0]  = *(const float4*)&Hs[k][ty * 4];
      *(float4*)&bb[0] = *(const float4*)&Ws[k][tx * 8];
      *(float4*)&bb[4] = *(const float4*)&Ws[k][tx * 8 + 4];
#pragma unroll
      for (int i = 0; i < 4; ++i)
#pragma unroll
        for (int j = 0; j < 8; ++j)
          acc[i][j] = fmaf(a[i], bb[j], acc[i][j]);
    }
    __syncthreads();
  }

#pragma unroll
  for (int i = 0; i < 4; ++i) {
    int b = ty * 4 + i;
    float* dst = &part[((size_t)ks * BB + b) * G4 + n0 + tx * 8];
    *(float4*)dst       = make_float4(acc[i][0], acc[i][1], acc[i][2], acc[i][3]);
    *(float4*)(dst + 4) = make_float4(acc[i][4], acc[i][5], acc[i][6], acc[i][7]);
  }
}

// ---------------------------------------------------------------------------
// Kernel 3: sum partials + Gin -> gates -> LSTM cell update.
// grid = 64 blocks x 256 threads; each thread handles 4 hidden units of one b.
// ---------------------------------------------------------------------------
__global__ __launch_bounds__(256) void step_combine(
    const float* __restrict__ gin, const float* __restrict__ part,
    float* __restrict__ h_state, float* __restrict__ c_state,
    float* __restrict__ out, int tloc, int t, int last)
{
  int idx = blockIdx.x * 256 + threadIdx.x;   // [0, 16384)
  int b = idx >> 8;
  int q = idx & 255;                          // float4 group within H

  size_t gb = ((size_t)tloc * BB + b) * G4 + q * 4;
  F4 gi, gf, gg, go;
  gi.v = *(const float4*)&gin[gb + 0 * HID];
  gf.v = *(const float4*)&gin[gb + 1 * HID];
  gg.v = *(const float4*)&gin[gb + 2 * HID];
  go.v = *(const float4*)&gin[gb + 3 * HID];

#pragma unroll
  for (int ks = 0; ks < 8; ++ks) {
    size_t pb = ((size_t)ks * BB + b) * G4 + q * 4;
    F4 pi, pf, pg, po;
    pi.v = *(const float4*)&part[pb + 0 * HID];
    pf.v = *(const float4*)&part[pb + 1 * HID];
    pg.v = *(const float4*)&part[pb + 2 * HID];
    po.v = *(const float4*)&part[pb + 3 * HID];
#pragma unroll
    for (int c = 0; c < 4; ++c) {
      gi.f[c] += pi.f[c]; gf.f[c] += pf.f[c];
      gg.f[c] += pg.f[c]; go.f[c] += po.f[c];
    }
  }

  F4 co;
  co.v = *(const float4*)&c_state[(size_t)b * HID + q * 4];

  float hv[4], cv[4];
#pragma unroll
  for (int c = 0; c < 4; ++c) {
    float iv = sigm(gi.f[c]);
    float fv = sigm(gf.f[c]);
    float gv = tanhf(gg.f[c]);
    float ov = sigm(go.f[c]);
    float cn = fv * co.f[c] + iv * gv;
    cv[c] = cn;
    hv[c] = ov * tanhf(cn);
  }

  float4 hq = make_float4(hv[0], hv[1], hv[2], hv[3]);
  float4 cq = make_float4(cv[0], cv[1], cv[2], cv[3]);

  *(float4*)&c_state[(size_t)b * HID + q * 4] = cq;
  *(float4*)&h_state[(size_t)b * HID + q * 4] = hq;
  // outputs[b][t][h]
  *(float4*)&out[((size_t)b * NSTEP + t) * HID + q * 4] = hq;

  if (last) {
    size_t tail = (size_t)BB * NSTEP * HID;
    *(float4*)&out[tail + (size_t)b * HID + q * 4] = hq;                       // h_n
    *(float4*)&out[tail + (size_t)BB * HID + (size_t)b * HID + q * 4] = cq;    // c_n
  }
}

// ---------------------------------------------------------------------------
extern "C" void kernel_launch(void* const* d_in, const int* in_sizes, int n_in,
                              void* d_out, int out_size, void* d_ws, size_t ws_size,
                              hipStream_t stream)
{
  const int*   tgt  = (const int*)d_in[0];
  const float* h0   = (const float*)d_in[1];
  const float* c0   = (const float*)d_in[2];
  // d_in[3] encoder_outputs, d_in[4] src_lengths: unused (attn=None)
  const float* emb  = (const float*)d_in[5];
  const float* w_ih = (const float*)d_in[6];
  const float* w_hh = (const float*)d_in[7];
  const float* b_ih = (const float*)d_in[8];
  const float* b_hh = (const float*)d_in[9];
  float* out = (float*)d_out;

  char* ws = (char*)d_ws;
  float* h_state = (float*)ws;  ws += (size_t)BB * HID * 4;
  float* c_state = (float*)ws;  ws += (size_t)BB * HID * 4;
  float* part    = (float*)ws;  ws += (size_t)8 * BB * G4 * 4;
  float* gin     = (float*)ws;
  size_t used = (size_t)(ws - (char*)d_ws);
  size_t gin_cap = (ws_size > used) ? (ws_size - used) : 0;
  int Tc = (int)(gin_cap / ((size_t)BB * G4 * 4));
  if (Tc > NSTEP) Tc = NSTEP;
  if (Tc < 1) return;  // workspace too small (not expected)

  hipMemcpyAsync(h_state, h0, (size_t)BB * HID * 4, hipMemcpyDeviceToDevice, stream);
  hipMemcpyAsync(c_state, c0, (size_t)BB * HID * 4, hipMemcpyDeviceToDevice, stream);

  for (int t0 = 0; t0 < NSTEP; t0 += Tc) {
    int tc = (NSTEP - t0 < Tc) ? (NSTEP - t0) : Tc;
    dim3 gg((tc * BB + 127) / 128, G4 / 128);
    gin_gemm<<<gg, 256, 0, stream>>>(tgt, emb, w_ih, b_ih, b_hh, gin, t0, tc);
    for (int t = t0; t < t0 + tc; ++t) {
      step_gemm<<<dim3(8, 32), 256, 0, stream>>>(h_state, w_hh, part);
      step_combine<<<dim3(64), 256, 0, stream>>>(gin, part, h_state, c_state, out,
                                                 t - t0, t, (t == NSTEP - 1) ? 1 : 0);
    }
  }
}

// Round 2
// 1335.555 us; speedup vs baseline: 2.7210x; 2.7210x over previous
//
#include <hip/hip_runtime.h>
#include <cstdint>
#include <cstddef>

#define HID   1024
#define G4    4096
#define BB    64
#define TSEQ  128
#define NSTEP 127

typedef __attribute__((ext_vector_type(4))) float f32x4;
typedef __attribute__((ext_vector_type(8))) short bf16x8;

__device__ __forceinline__ unsigned short f2bf(float x) {
  union { float f; unsigned u; } v; v.f = x;
  unsigned r = v.u + 0x7FFF + ((v.u >> 16) & 1);   // RNE
  return (unsigned short)(r >> 16);
}

// ---------------------------------------------------------------------------
// f32 -> bf16 bulk convert (n multiple of 8)
// ---------------------------------------------------------------------------
__global__ __launch_bounds__(256) void conv_f32_bf16(
    const float* __restrict__ in, unsigned short* __restrict__ out, int n)
{
  int i = (blockIdx.x * 256 + threadIdx.x) * 8;
  if (i >= n) return;
  float4 v0 = *reinterpret_cast<const float4*>(&in[i]);
  float4 v1 = *reinterpret_cast<const float4*>(&in[i + 4]);
  unsigned short u[8];
  u[0] = f2bf(v0.x); u[1] = f2bf(v0.y); u[2] = f2bf(v0.z); u[3] = f2bf(v0.w);
  u[4] = f2bf(v1.x); u[5] = f2bf(v1.y); u[6] = f2bf(v1.z); u[7] = f2bf(v1.w);
  *reinterpret_cast<bf16x8*>(&out[i]) = *reinterpret_cast<bf16x8*>(u);
}

__global__ __launch_bounds__(256) void bias_add(
    const float* __restrict__ b_ih, const float* __restrict__ b_hh,
    float* __restrict__ bias)
{
  int i = blockIdx.x * 256 + threadIdx.x;
  if (i < G4) bias[i] = b_ih[i] + b_hh[i];
}

// ---------------------------------------------------------------------------
// Gather embedding rows for steps [t0, t0+tc) -> bf16 A matrix [Mt][HID],
// rows m = tl*64 + b; pad rows (>= tc*64) zero-filled. padding_idx=0 -> zeros.
// ---------------------------------------------------------------------------
__global__ __launch_bounds__(256) void conv_A(
    const int* __restrict__ tgt, const float* __restrict__ emb,
    unsigned short* __restrict__ A, int t0, int tc)
{
  int i = blockIdx.x * 256 + threadIdx.x;   // i indexes 8-element groups
  int m  = i >> 7;
  int k8 = (i & 127) * 8;
  int tl = m >> 6, b = m & 63;
  float4 v0 = make_float4(0.f, 0.f, 0.f, 0.f), v1 = v0;
  if (tl < tc) {
    int tok = tgt[b * TSEQ + t0 + tl];
    if (tok != 0) {
      const float* src = &emb[(size_t)tok * HID + k8];
      v0 = *reinterpret_cast<const float4*>(src);
      v1 = *reinterpret_cast<const float4*>(src + 4);
    }
  }
  unsigned short u[8];
  u[0] = f2bf(v0.x); u[1] = f2bf(v0.y); u[2] = f2bf(v0.z); u[3] = f2bf(v0.w);
  u[4] = f2bf(v1.x); u[5] = f2bf(v1.y); u[6] = f2bf(v1.z); u[7] = f2bf(v1.w);
  *reinterpret_cast<bf16x8*>(&A[(size_t)m * HID + k8]) = *reinterpret_cast<bf16x8*>(u);
}

// ---------------------------------------------------------------------------
// Input GEMM, bf16 MFMA 16x16x32: gin[m][n] = sum_k A[m][k]*W[n][k] + bias[n].
// 128x128 tile, 256 threads = 4 waves (2x2), BK=32, LDS row-stride 40 bf16
// (80 B -> 16B-aligned b128 reads, 2-way bank aliasing = free).
// ---------------------------------------------------------------------------
__global__ __launch_bounds__(256) void gin_mfma(
    const unsigned short* __restrict__ A, const unsigned short* __restrict__ W,
    const float* __restrict__ bias, float* __restrict__ gin, int Mvalid)
{
  __shared__ unsigned short As[128 * 40];
  __shared__ unsigned short Bs[128 * 40];

  const int tid = threadIdx.x;
  const int m0 = blockIdx.x * 128, n0 = blockIdx.y * 128;
  const int l  = tid & 63, w = tid >> 6;
  const int wr = w >> 1, wc = w & 1;
  const int lr = l & 15, lh = l >> 4;

  f32x4 acc[4][4];
#pragma unroll
  for (int i = 0; i < 4; ++i)
#pragma unroll
    for (int j = 0; j < 4; ++j) acc[i][j] = (f32x4)0.f;

  for (int kc = 0; kc < HID; kc += 32) {
#pragma unroll
    for (int it = 0; it < 2; ++it) {
      int c = tid + it * 256;          // 512 16B chunks per tile
      int row = c >> 2, k8 = (c & 3) * 8;
      *reinterpret_cast<bf16x8*>(&As[row * 40 + k8]) =
          *reinterpret_cast<const bf16x8*>(&A[(size_t)(m0 + row) * HID + kc + k8]);
      *reinterpret_cast<bf16x8*>(&Bs[row * 40 + k8]) =
          *reinterpret_cast<const bf16x8*>(&W[(size_t)(n0 + row) * HID + kc + k8]);
    }
    __syncthreads();

    bf16x8 af[4], bfr[4];
#pragma unroll
    for (int i = 0; i < 4; ++i) {
      af[i]  = *reinterpret_cast<const bf16x8*>(&As[(wr * 64 + i * 16 + lr) * 40 + lh * 8]);
      bfr[i] = *reinterpret_cast<const bf16x8*>(&Bs[(wc * 64 + i * 16 + lr) * 40 + lh * 8]);
    }
#pragma unroll
    for (int i = 0; i < 4; ++i)
#pragma unroll
      for (int j = 0; j < 4; ++j)
        acc[i][j] = __builtin_amdgcn_mfma_f32_16x16x32_bf16(af[i], bfr[j], acc[i][j], 0, 0, 0);
    __syncthreads();
  }

#pragma unroll
  for (int j = 0; j < 4; ++j) {
    int n = n0 + wc * 64 + j * 16 + lr;
    float bn = bias[n];
#pragma unroll
    for (int i = 0; i < 4; ++i) {
      int mb = m0 + wr * 64 + i * 16 + lh * 4;
#pragma unroll
      for (int r = 0; r < 4; ++r) {
        int m = mb + r;
        if (m < Mvalid) gin[(size_t)m * G4 + n] = acc[i][j][r] + bn;
      }
    }
  }
}

// ---------------------------------------------------------------------------
// Fused LSTM step: gates = h@w_hh^T (bf16 MFMA) + gin; activations; state
// update. grid = 128 blocks: block owns units u0=(blk>>1)*16, batch half
// mh=blk&1 (32 batches). 4 waves K-split (256 each); LDS cross-wave reduce.
// h double-buffered in bf16 across steps (read hbf_in, write hbf_out).
// ---------------------------------------------------------------------------
__global__ __launch_bounds__(256) void lstm_step(
    const unsigned short* __restrict__ hbf_in, unsigned short* __restrict__ hbf_out,
    const unsigned short* __restrict__ whh, const float* __restrict__ gin,
    float* __restrict__ c_state, float* __restrict__ out,
    int tloc, int t, int last)
{
  __shared__ float red[4][4][32][16];   // [wave][gate][b][u]

  const int tid = threadIdx.x;
  const int l = tid & 63, w = tid >> 6;
  const int lr = l & 15, lh = l >> 4;
  const int u0 = (blockIdx.x >> 1) * 16;
  const int mh = blockIdx.x & 1;
  const int kbase = w * 256;

  f32x4 acc[2][4];
#pragma unroll
  for (int i = 0; i < 2; ++i)
#pragma unroll
    for (int j = 0; j < 4; ++j) acc[i][j] = (f32x4)0.f;

  for (int kc = 0; kc < 256; kc += 32) {
    int k = kbase + kc + lh * 8;
    bf16x8 af[2], bfr[4];
#pragma unroll
    for (int i = 0; i < 2; ++i)
      af[i] = *reinterpret_cast<const bf16x8*>(&hbf_in[(size_t)(mh * 32 + i * 16 + lr) * HID + k]);
#pragma unroll
    for (int j = 0; j < 4; ++j)
      bfr[j] = *reinterpret_cast<const bf16x8*>(&whh[(size_t)(j * HID + u0 + lr) * HID + k]);
#pragma unroll
    for (int i = 0; i < 2; ++i)
#pragma unroll
      for (int j = 0; j < 4; ++j)
        acc[i][j] = __builtin_amdgcn_mfma_f32_16x16x32_bf16(af[i], bfr[j], acc[i][j], 0, 0, 0);
  }

#pragma unroll
  for (int i = 0; i < 2; ++i)
#pragma unroll
    for (int j = 0; j < 4; ++j)
#pragma unroll
      for (int r = 0; r < 4; ++r)
        red[w][j][i * 16 + lh * 4 + r][lr] = acc[i][j][r];
  __syncthreads();

#pragma unroll
  for (int cc = 0; cc < 2; ++cc) {
    int cell = tid * 2 + cc;        // 512 cells: 32 b x 16 u
    int b = cell >> 4;
    int u = cell & 15;
    int gb = mh * 32 + b;           // global batch
    float g[4];
#pragma unroll
    for (int j = 0; j < 4; ++j) {
      float s = red[0][j][b][u] + red[1][j][b][u] + red[2][j][b][u] + red[3][j][b][u];
      g[j] = s + gin[((size_t)(tloc * BB + gb)) * G4 + j * HID + u0 + u];
    }
    size_t ci = (size_t)gb * HID + u0 + u;
    float c_old = c_state[ci];
    float iv = 1.f / (1.f + expf(-g[0]));
    float fv = 1.f / (1.f + expf(-g[1]));
    float gv = tanhf(g[2]);
    float ov = 1.f / (1.f + expf(-g[3]));
    float cn = fv * c_old + iv * gv;
    float hn = ov * tanhf(cn);
    c_state[ci] = cn;
    hbf_out[ci] = f2bf(hn);
    out[((size_t)gb * NSTEP + t) * HID + u0 + u] = hn;
    if (last) {
      size_t tail = (size_t)BB * NSTEP * HID;
      out[tail + ci] = hn;                          // h_n
      out[tail + (size_t)BB * HID + ci] = cn;       // c_n
    }
  }
}

// ---------------------------------------------------------------------------
extern "C" void kernel_launch(void* const* d_in, const int* in_sizes, int n_in,
                              void* d_out, int out_size, void* d_ws, size_t ws_size,
                              hipStream_t stream)
{
  const int*   tgt  = (const int*)d_in[0];
  const float* h0   = (const float*)d_in[1];
  const float* c0   = (const float*)d_in[2];
  const float* emb  = (const float*)d_in[5];
  const float* w_ih = (const float*)d_in[6];
  const float* w_hh = (const float*)d_in[7];
  const float* b_ih = (const float*)d_in[8];
  const float* b_hh = (const float*)d_in[9];
  float* out = (float*)d_out;

  char* p = (char*)d_ws;
  unsigned short* wih_bf = (unsigned short*)p; p += (size_t)G4 * HID * 2;
  unsigned short* whh_bf = (unsigned short*)p; p += (size_t)G4 * HID * 2;
  float*          bias   = (float*)p;          p += (size_t)G4 * 4;
  unsigned short* hbf0   = (unsigned short*)p; p += (size_t)BB * HID * 2;
  unsigned short* hbf1   = (unsigned short*)p; p += (size_t)BB * HID * 2;
  float*          c_st   = (float*)p;          p += (size_t)BB * HID * 4;

  size_t fixed = (size_t)(p - (char*)d_ws);
  size_t rem = (ws_size > fixed) ? ws_size - fixed : 0;
  // per chunk of Tc steps: A_bf = Mt*HID*2 bytes (Mt = ceil(Tc*64/128)*128),
  // gin = Tc*64*4096*4 bytes. cost(Tc) <= Tc*1179648 + 262144.
  int Tc = (int)((rem > 262144 ? rem - 262144 : 0) / 1179648);
  if (Tc > NSTEP) Tc = NSTEP;
  if (Tc < 1) return;

  int MtMax = ((Tc * BB + 127) / 128) * 128;
  unsigned short* A_bf = (unsigned short*)p; p += (size_t)MtMax * HID * 2;
  float*          gin  = (float*)p;

  conv_f32_bf16<<<dim3((G4 * HID) / 8 / 256), 256, 0, stream>>>(w_ih, wih_bf, G4 * HID);
  conv_f32_bf16<<<dim3((G4 * HID) / 8 / 256), 256, 0, stream>>>(w_hh, whh_bf, G4 * HID);
  bias_add<<<dim3(G4 / 256), 256, 0, stream>>>(b_ih, b_hh, bias);
  conv_f32_bf16<<<dim3((BB * HID) / 8 / 256), 256, 0, stream>>>(h0, hbf0, BB * HID);
  hipMemcpyAsync(c_st, c0, (size_t)BB * HID * 4, hipMemcpyDeviceToDevice, stream);

  int cur = 0;
  for (int t0 = 0; t0 < NSTEP; t0 += Tc) {
    int tc = (NSTEP - t0 < Tc) ? (NSTEP - t0) : Tc;
    int Mt = ((tc * BB + 127) / 128) * 128;
    conv_A<<<dim3(Mt / 2), 256, 0, stream>>>(tgt, emb, A_bf, t0, tc);
    gin_mfma<<<dim3(Mt / 128, G4 / 128), 256, 0, stream>>>(A_bf, wih_bf, bias, gin, tc * BB);
    for (int tl = 0; tl < tc; ++tl) {
      int t = t0 + tl;
      unsigned short* hin  = cur ? hbf1 : hbf0;
      unsigned short* hout = cur ? hbf0 : hbf1;
      lstm_step<<<dim3(128), 256, 0, stream>>>(hin, hout, whh_bf, gin, c_st, out,
                                               tl, t, (t == NSTEP - 1) ? 1 : 0);
      cur ^= 1;
    }
  }
}